// Round 4
// baseline (144.366 us; speedup 1.0000x reference)
//
#include <hip/hip_runtime.h>
#include <hip/hip_bf16.h>

// DCNv2 forward: B=2, C=256, H=W=96, O=256, K=3x3, stride=1, pad=1, dil=1.
// Pipeline:
//  K1 prep     : (a) input NCHW fp32 -> NHWC bf16,
//                (b) weight -> bf16 32x32-FRAGMENT order wt[kk][cc16][osub][lane][8]
//  K2 dcn_main : per tap: fill BOTH batches' 32s x 256ch tap tiles into LDS,
//                then MFMA chunks; each weight fragment feeds 2 MFMAs (batch 0+1).
// R9 theory: R5/R6/R8 all ~55-58us across different schedules/occupancy ->
//   shared-resource bound: L2 reads ~1GB/58us = 17 TB/s ~ 50% aggregate ceiling.
//   Weights dominate (128KB/block/tap x 576 blocks x 9 = 663MB). Fusing both
//   batches into one block halves W traffic (same slice feeds 2 B-tiles):
//   total L2 reads ~0.68x. colT now batch-indexed (no tap dbuf, 2 barriers/tap,
//   51.2KB LDS -> still 2 blocks/CU). Wave partition (osub-pair x C-half) kept;
//   cross-wave C-half reduce at end, per batch, through dead colT.
// R8 lesson: occupancy 2x (spill-free) gave ZERO speedup -> not latency-bound.
// R7 lesson: launch_bounds min-waves too high => VGPR budget -> scratch spill
//   (FETCH 13->113MB). Keep budget loose: (512,3) ~ 170 VGPR.
// R6 lesson: compiler sinks source-level load pipelining; keep simple schedule.

#define Hh 96
#define Ww 96
#define Cc 256
#define Oo 256
#define Bb 2
#define Kk 9
#define Ss (Hh * Ww)          // 9216
#define CKTOT (Cc * Kk)       // 2304

typedef __bf16 bf16x8 __attribute__((ext_vector_type(8)));
typedef __bf16 bf16x2v __attribute__((ext_vector_type(2)));
typedef float f32x16 __attribute__((ext_vector_type(16)));
typedef float f32x2 __attribute__((ext_vector_type(2)));

__device__ __forceinline__ f32x2 up2(unsigned u) {
  f32x2 r;
  r.x = __uint_as_float(u << 16);
  r.y = __uint_as_float(u & 0xffff0000u);
  return r;
}

// barrier with LDS drain only — prefetched global loads stay in flight.
// simm16 0xC07F = lgkmcnt(0), expcnt(0), vmcnt(63)=no-wait.
__device__ __forceinline__ void barrier_lgkm() {
  asm volatile("" ::: "memory");
  __builtin_amdgcn_s_waitcnt(0xC07F);
  __builtin_amdgcn_s_barrier();
  asm volatile("" ::: "memory");
}

// ---------------- K1: merged prep ----------------
// blocks [0,1152)    : transpose NCHW fp32 -> NHWC bf16
// blocks [1152,3456) : weight repack to 32x32 A-fragment order:
//   wt[kk][cc][osub][lane][j]: o = osub*32 + (lane&31), ch = cc*16 + (lane>>5)*8 + j
__global__ __launch_bounds__(256) void prep(const float* __restrict__ inp,
                                            const float* __restrict__ wsrc,
                                            __bf16* __restrict__ it,
                                            __bf16* __restrict__ wt) {
  __shared__ float tile[64][65];
  const int bx = blockIdx.x;
  const int tid = threadIdx.x;

  if (bx < 1152) {
    const int hw0 = (bx % 144) * 64;
    const int c0 = ((bx / 144) & 3) * 64;
    const int b = bx / 576;
    const int hw_l = tid & 63, cr = tid >> 6;
    const float* src = inp + ((size_t)(b * Cc + c0) * Ss) + hw0;
#pragma unroll
    for (int r = 0; r < 16; ++r) {
      int c_l = r * 4 + cr;
      tile[c_l][hw_l] = src[(size_t)c_l * Ss + hw_l];
    }
    __syncthreads();
    const int cp = (tid & 31) * 2, hr = tid >> 5;
    __bf16* dst = it + ((size_t)(b * Ss + hw0) * Cc) + c0;
#pragma unroll
    for (int r = 0; r < 8; ++r) {
      int hw_s = r * 8 + hr;
      bf16x2v p;
      p.x = (__bf16)tile[cp][hw_s];
      p.y = (__bf16)tile[cp + 1][hw_s];
      *(bf16x2v*)(dst + (size_t)hw_s * Cc + cp) = p;
    }
  } else {
    int i = (bx - 1152) * 256 + tid;  // i < Oo*CKTOT = 589824
    int j = i & 7;
    int l = (i >> 3) & 63;
    int osub = (i >> 9) & 7;
    int cc = (i >> 12) & 15;
    int kk = i >> 16;
    int o = osub * 32 + (l & 31);
    int ch = cc * 16 + ((l >> 5) << 3) + j;
    wt[i] = (__bf16)wsrc[(o * Cc + ch) * Kk + kk];
  }
}

// ---------------- K2: fused sample + GEMM, both batches per block ----------------
// grid (288): 32-s tile (XCD-swizzled). 512 thr = 8 waves:
//   wq = wv&3 -> osub pair {wq*2, wq*2+1} (o in [wq*64, wq*64+64))
//   chh = wv>>2 -> cc half (0..7 / 8..15)
// Each wave computes its W-slice against BOTH batches' B-tiles (W read once).
__global__ __launch_bounds__(512, 3) void dcn_main(
    const __bf16* __restrict__ it,     // [B][S][C] bf16
    const __bf16* __restrict__ wt,     // 32x32-fragment-order weights
    const float* __restrict__ offset,  // [B][18][S]
    const float* __restrict__ mask,    // [B][9][S]
    const float* __restrict__ bias,    // [O]
    float* __restrict__ out)           // [B][O][S]
{
  __shared__ __bf16 colT[2][32 * 256];  // per-BATCH tap tile, XOR-swizzled granules
  __shared__ int4 pa9[2][9][32];        // per-batch, per-tap corner offsets
  __shared__ float4 pw9[2][9][32];      // per-batch, per-tap corner weights

  const int tid = threadIdx.x;
  // XCD swizzle: XCD j gets 36 contiguous 32-s tiles (288 = 8*36 exactly).
  const int tile = (blockIdx.x & 7) * 36 + (blockIdx.x >> 3);
  const int s0 = tile * 32;
  const int lane = tid & 63;
  const int wv = tid >> 6;            // 0..7
  const int wq = wv & 3;              // osub pair
  const int chh = wv >> 2;            // cc half
  const int cbase = chh * 8;
  const int sB = lane & 31;
  const int hi = lane >> 5;
  const int fs = tid >> 4;            // fill: s-row 0..31
  const int fg = tid & 15;            // fill: granule group 0..15

  // ---- bilinear params: 2 batches x 9 taps x 32 s ----
  for (int idx = tid; idx < 2 * 9 * 32; idx += 512) {
    int bt = idx >= 288 ? 1 : 0;
    int rem = idx - bt * 288;
    int kk = rem >> 5;
    int sl = rem & 31;
    int s = s0 + sl;
    int ho = s / Ww;
    int wo = s - ho * Ww;
    float dy = offset[((size_t)(bt * 18 + 2 * kk)) * Ss + s];
    float dx = offset[((size_t)(bt * 18 + 2 * kk + 1)) * Ss + s];
    float m = mask[((size_t)(bt * 9 + kk)) * Ss + s];
    float y = (float)(ho - 1 + kk / 3) + dy;
    float x = (float)(wo - 1 + kk % 3) + dx;
    float fy = floorf(y), fx = floorf(x);
    int y0 = (int)fy, x0 = (int)fx;
    float wy = y - fy, wx = x - fx;
    int y1 = y0 + 1, x1 = x0 + 1;
    float vy0 = (y0 >= 0 && y0 < Hh) ? 1.f : 0.f;
    float vy1 = (y1 >= 0 && y1 < Hh) ? 1.f : 0.f;
    float vx0 = (x0 >= 0 && x0 < Ww) ? 1.f : 0.f;
    float vx1 = (x1 >= 0 && x1 < Ww) ? 1.f : 0.f;
    int y0c = min(max(y0, 0), Hh - 1), y1c = min(max(y1, 0), Hh - 1);
    int x0c = min(max(x0, 0), Ww - 1), x1c = min(max(x1, 0), Ww - 1);
    pa9[bt][kk][sl] = make_int4((y0c * Ww + x0c) * Cc, (y0c * Ww + x1c) * Cc,
                                (y1c * Ww + x0c) * Cc, (y1c * Ww + x1c) * Cc);
    pw9[bt][kk][sl] = make_float4(m * (1.f - wy) * (1.f - wx) * vy0 * vx0,
                                  m * (1.f - wy) * wx * vy0 * vx1,
                                  m * wy * (1.f - wx) * vy1 * vx0,
                                  m * wy * wx * vy1 * vx1);
  }
  __syncthreads();

  f32x16 acc00, acc01, acc10, acc11;  // acc[which][batch]
#pragma unroll
  for (int j = 0; j < 16; ++j) {
    acc00[j] = 0.f; acc01[j] = 0.f; acc10[j] = 0.f; acc11[j] = 0.f;
  }

  // weight A-fragment load: wt[((kk*16+cc)*8 + osub)*512 + lane*8]
  auto ldW = [&](int kk, int cc, int which) {
    size_t idx = (size_t)((kk * 16 + cc) * 8 + wq * 2 + which);
    return *(const bf16x8*)(wt + (idx << 9) + (lane << 3));
  };
  // B fragment from LDS: batch bt, row sB, logical granule 2cc+hi, XOR-swizzled
  auto ldB = [&](int bt, int cc) {
    int g = ((2 * cc + hi) ^ (sB & 7)) << 3;
    return *(const bf16x8*)(&colT[bt][sB * 256 + g]);
  };

  for (int kk = 0; kk < Kk; ++kk) {
    // ---- fill: both batches, 16 burst dwordx4 corner loads/thread ----
#pragma unroll
    for (int bt = 0; bt < 2; ++bt) {
      int4 a = pa9[bt][kk][fs];
      float4 wqv = pw9[bt][kk][fs];
      const __bf16* pb = it + (size_t)bt * Ss * Cc;
      __bf16* drow = &colT[bt][fs * 256];
#pragma unroll
      for (int it2 = 0; it2 < 2; ++it2) {
        int g = fg + it2 * 16;          // logical granule (8 ch)
        const __bf16* p = pb + g * 8;
        uint4 c00 = *(const uint4*)(p + a.x);
        uint4 c01 = *(const uint4*)(p + a.y);
        uint4 c10 = *(const uint4*)(p + a.z);
        uint4 c11 = *(const uint4*)(p + a.w);
        unsigned u0[4] = {c00.x, c00.y, c00.z, c00.w};
        unsigned u1[4] = {c01.x, c01.y, c01.z, c01.w};
        unsigned u2[4] = {c10.x, c10.y, c10.z, c10.w};
        unsigned u3[4] = {c11.x, c11.y, c11.z, c11.w};
        bf16x8 rv;
#pragma unroll
        for (int w = 0; w < 4; ++w) {
          f32x2 r = up2(u0[w]) * wqv.x + up2(u1[w]) * wqv.y +
                    up2(u2[w]) * wqv.z + up2(u3[w]) * wqv.w;
          rv[2 * w] = (__bf16)r.x;
          rv[2 * w + 1] = (__bf16)r.y;
        }
        *(bf16x8*)(drow + ((g ^ (fs & 7)) << 3)) = rv;
      }
    }
    // chunk-0 weights issued pre-barrier; lgkm-only barrier keeps them in flight
    bf16x8 Wacur = ldW(kk, cbase, 0);
    bf16x8 Wbcur = ldW(kk, cbase, 1);
    barrier_lgkm();

    // ---- compute: 8 chunks; each W pair feeds both batches (4 MFMA/chunk) ----
    bf16x8 B0cur = ldB(0, cbase);
    bf16x8 B1cur = ldB(1, cbase);
#pragma unroll
    for (int cc = 0; cc < 8; ++cc) {
      bf16x8 Wan, Wbn, B0n, B1n;
      if (cc < 7) {
        Wan = ldW(kk, cbase + cc + 1, 0);
        Wbn = ldW(kk, cbase + cc + 1, 1);
        B0n = ldB(0, cbase + cc + 1);
        B1n = ldB(1, cbase + cc + 1);
      }
      acc00 = __builtin_amdgcn_mfma_f32_32x32x16_bf16(Wacur, B0cur, acc00, 0, 0, 0);
      acc01 = __builtin_amdgcn_mfma_f32_32x32x16_bf16(Wacur, B1cur, acc01, 0, 0, 0);
      acc10 = __builtin_amdgcn_mfma_f32_32x32x16_bf16(Wbcur, B0cur, acc10, 0, 0, 0);
      acc11 = __builtin_amdgcn_mfma_f32_32x32x16_bf16(Wbcur, B1cur, acc11, 0, 0, 0);
      if (cc < 7) {
        Wacur = Wan; Wbcur = Wbn; B0cur = B0n; B1cur = B1n;
      }
    }
    // WAR barrier: all LDS reads of this tap done before next tap's fill writes
    barrier_lgkm();
  }

  // ---- cross-wave C-half reduction, per batch, through dead colT (32KB) ----
  // D mapping (32x32): col(s)=lane&31, row(o-off)=(r&3)+8*(r>>2)+4*(lane>>5)
  float* red = (float*)colT;       // red[(which*16+r)*256 + wq*64 + lane]
  // batch 0
  if (chh == 1) {
#pragma unroll
    for (int which = 0; which < 2; ++which)
#pragma unroll
      for (int r = 0; r < 16; ++r)
        red[(which * 16 + r) * 256 + wq * 64 + lane] =
            (which ? acc10[r] : acc00[r]);
  }
  __syncthreads();
  if (chh == 0) {
    float* ob = out + s0 + sB;
#pragma unroll
    for (int which = 0; which < 2; ++which) {
#pragma unroll
      for (int r = 0; r < 16; ++r) {
        int o = wq * 64 + which * 32 + (r & 3) + 8 * (r >> 2) + 4 * hi;
        float v = (which ? acc10[r] : acc00[r]) +
                  red[(which * 16 + r) * 256 + wq * 64 + lane] + bias[o];
        ob[(size_t)o * Ss] = v;
      }
    }
  }
  __syncthreads();
  // batch 1
  if (chh == 1) {
#pragma unroll
    for (int which = 0; which < 2; ++which)
#pragma unroll
      for (int r = 0; r < 16; ++r)
        red[(which * 16 + r) * 256 + wq * 64 + lane] =
            (which ? acc11[r] : acc01[r]);
  }
  __syncthreads();
  if (chh == 0) {
    float* ob = out + (size_t)Oo * Ss + s0 + sB;
#pragma unroll
    for (int which = 0; which < 2; ++which) {
#pragma unroll
      for (int r = 0; r < 16; ++r) {
        int o = wq * 64 + which * 32 + (r & 3) + 8 * (r >> 2) + 4 * hi;
        float v = (which ? acc11[r] : acc01[r]) +
                  red[(which * 16 + r) * 256 + wq * 64 + lane] + bias[o];
        ob[(size_t)o * Ss] = v;
      }
    }
  }
}

extern "C" void kernel_launch(void* const* d_in, const int* in_sizes, int n_in,
                              void* d_out, int out_size, void* d_ws, size_t ws_size,
                              hipStream_t stream) {
  (void)in_sizes; (void)n_in; (void)out_size; (void)ws_size;
  const float* inp = (const float*)d_in[0];
  const float* offset = (const float*)d_in[1];
  const float* mask = (const float*)d_in[2];
  const float* weight = (const float*)d_in[3];
  const float* bias = (const float*)d_in[4];
  float* out = (float*)d_out;

  __bf16* it = (__bf16*)d_ws;                                      // 9,437,184 B
  __bf16* wt = (__bf16*)((char*)d_ws + (size_t)Bb * Ss * Cc * 2);  // 1,179,648 B

  prep<<<3456, 256, 0, stream>>>(inp, weight, it, wt);
  dcn_main<<<288, 512, 0, stream>>>(it, wt, offset, mask, bias, out);
}

// Round 6
// 139.538 us; speedup vs baseline: 1.0346x; 1.0346x over previous
//
#include <hip/hip_runtime.h>
#include <hip/hip_bf16.h>

// DCNv2 forward: B=2, C=256, H=W=96, O=256, K=3x3, stride=1, pad=1, dil=1.
// Pipeline:
//  K1 prep     : (a) input NCHW fp32 -> NHWC bf16,
//                (b) weight -> bf16 32x32-FRAGMENT order wt[kk][cc16][osub][lane][8]
//  K2 dcn_main : per tap: burst-fill 32s x 256ch tap tile into LDS, preload the
//                ENTIRE tap W slice (32 fragments, 128 VGPR) pre-barrier, then a
//                global-load-free MFMA loop with LDS prefetch-2.
// R11 = R10 re-run: previous bench died with "MI355X container failed twice"
//   (broker/infra, no compile or correctness diagnostic). Kernel is hang-free
//   (uniform barriers, bounded loops) and fits the (256,2) VGPR budget
//   (~200 natural). Re-running unchanged to actually test the R10 hypothesis.
// R10 theory: R5/R8 ~55-58us invariant to occupancy (R8) and bytes (R9) ->
//   bottleneck is per-chunk W-load latency (L2 ~250cy, lookahead-1 covers 16cy).
//   Fix: issue all 32 W dwordx4 BEFORE barrier_lgkm -- its asm "memory" clobber
//   is a compiler fence, so loads CANNOT sink past it (R6's pipelining had no
//   fence between issue and use, hence got sunk). W latency hides under
//   bilinear+barrier; chunk loop = ds_read(prefetch-2) + MFMA only.
// R9 lesson: byte reduction (W traffic /2) made it SLOWER -> not L2-BW-bound;
//   dbuf overlap + block count matter more than bytes.
// R8 lesson: occupancy 2x gave zero -> not TLP-starved. R7: tight launch_bounds
//   min-waves => spill (FETCH 13->113MB). Here: (256,2) = 256-VGPR budget for
//   ~200 natural; watch FETCH_SIZE as the spill tripwire.

#define Hh 96
#define Ww 96
#define Cc 256
#define Oo 256
#define Bb 2
#define Kk 9
#define Ss (Hh * Ww)          // 9216
#define CKTOT (Cc * Kk)       // 2304

typedef __bf16 bf16x8 __attribute__((ext_vector_type(8)));
typedef __bf16 bf16x2v __attribute__((ext_vector_type(2)));
typedef float f32x16 __attribute__((ext_vector_type(16)));
typedef float f32x2 __attribute__((ext_vector_type(2)));

__device__ __forceinline__ f32x2 up2(unsigned u) {
  f32x2 r;
  r.x = __uint_as_float(u << 16);
  r.y = __uint_as_float(u & 0xffff0000u);
  return r;
}

// barrier with LDS drain only — prefetched global loads stay in flight.
// simm16 0xC07F = lgkmcnt(0), expcnt(0), vmcnt(63)=no-wait.
// The asm "memory" clobbers double as compiler fences: loads issued before
// this cannot be sunk past it.
__device__ __forceinline__ void barrier_lgkm() {
  asm volatile("" ::: "memory");
  __builtin_amdgcn_s_waitcnt(0xC07F);
  __builtin_amdgcn_s_barrier();
  asm volatile("" ::: "memory");
}

// ---------------- K1: merged prep ----------------
// blocks [0,1152)    : transpose NCHW fp32 -> NHWC bf16
// blocks [1152,3456) : weight repack to 32x32 A-fragment order:
//   wt[kk][cc][osub][lane][j]: o = osub*32 + (lane&31), ch = cc*16 + (lane>>5)*8 + j
__global__ __launch_bounds__(256) void prep(const float* __restrict__ inp,
                                            const float* __restrict__ wsrc,
                                            __bf16* __restrict__ it,
                                            __bf16* __restrict__ wt) {
  __shared__ float tile[64][65];
  const int bx = blockIdx.x;
  const int tid = threadIdx.x;

  if (bx < 1152) {
    const int hw0 = (bx % 144) * 64;
    const int c0 = ((bx / 144) & 3) * 64;
    const int b = bx / 576;
    const int hw_l = tid & 63, cr = tid >> 6;
    const float* src = inp + ((size_t)(b * Cc + c0) * Ss) + hw0;
#pragma unroll
    for (int r = 0; r < 16; ++r) {
      int c_l = r * 4 + cr;
      tile[c_l][hw_l] = src[(size_t)c_l * Ss + hw_l];
    }
    __syncthreads();
    const int cp = (tid & 31) * 2, hr = tid >> 5;
    __bf16* dst = it + ((size_t)(b * Ss + hw0) * Cc) + c0;
#pragma unroll
    for (int r = 0; r < 8; ++r) {
      int hw_s = r * 8 + hr;
      bf16x2v p;
      p.x = (__bf16)tile[cp][hw_s];
      p.y = (__bf16)tile[cp + 1][hw_s];
      *(bf16x2v*)(dst + (size_t)hw_s * Cc + cp) = p;
    }
  } else {
    int i = (bx - 1152) * 256 + tid;  // i < Oo*CKTOT = 589824
    int j = i & 7;
    int l = (i >> 3) & 63;
    int osub = (i >> 9) & 7;
    int cc = (i >> 12) & 15;
    int kk = i >> 16;
    int o = osub * 32 + (l & 31);
    int ch = cc * 16 + ((l >> 5) << 3) + j;
    wt[i] = (__bf16)wsrc[(o * Cc + ch) * Kk + kk];
  }
}

// ---------------- K2: fused sample + GEMM ----------------
// grid (288, 2): x = 32-s tile (XCD-swizzled), y = batch.
// 256 thr = 4 waves; wave wv covers o in [wv*64, wv*64+64); block = 32s x 256 O.
__global__ __launch_bounds__(256, 2) void dcn_main(
    const __bf16* __restrict__ it,     // [B][S][C] bf16
    const __bf16* __restrict__ wt,     // 32x32-fragment-order weights
    const float* __restrict__ offset,  // [B][18][S]
    const float* __restrict__ mask,    // [B][9][S]
    const float* __restrict__ bias,    // [O]
    float* __restrict__ out)           // [B][O][S]
{
  __shared__ __bf16 colT[2][32 * 256];  // dbuf tap tile, XOR-swizzled granules
  __shared__ int4 pa9[9][32];           // per-tap corner offsets (elements)
  __shared__ float4 pw9[9][32];         // per-tap corner weights (mask+valid folded)

  const int tid = threadIdx.x;
  // XCD swizzle: XCD j gets 36 contiguous 32-s tiles (~2.6MB L2 working set).
  const int tile = (blockIdx.x & 7) * 36 + (blockIdx.x >> 3);
  const int s0 = tile * 32;
  const int b = blockIdx.y;
  const int lane = tid & 63;
  const int wv = tid >> 6;            // 4 waves -> 64 O each
  const int sB = lane & 31;           // B-frag / C-frag spatial lane
  const int hi = lane >> 5;
  const int fs = tid >> 3;            // fill: s-row 0..31
  const int fg = tid & 7;             // fill: granule group 0..7

  const __bf16* itb = it + (size_t)b * Ss * Cc;

  // ---- bilinear params for all 9 taps up front ----
  for (int idx = tid; idx < 9 * 32; idx += 256) {
    int kk = idx >> 5;
    int sl = idx & 31;
    int s = s0 + sl;
    int ho = s / Ww;
    int wo = s - ho * Ww;
    float dy = offset[((size_t)(b * 18 + 2 * kk)) * Ss + s];
    float dx = offset[((size_t)(b * 18 + 2 * kk + 1)) * Ss + s];
    float m = mask[((size_t)(b * 9 + kk)) * Ss + s];
    float y = (float)(ho - 1 + kk / 3) + dy;
    float x = (float)(wo - 1 + kk % 3) + dx;
    float fy = floorf(y), fx = floorf(x);
    int y0 = (int)fy, x0 = (int)fx;
    float wy = y - fy, wx = x - fx;
    int y1 = y0 + 1, x1 = x0 + 1;
    float vy0 = (y0 >= 0 && y0 < Hh) ? 1.f : 0.f;
    float vy1 = (y1 >= 0 && y1 < Hh) ? 1.f : 0.f;
    float vx0 = (x0 >= 0 && x0 < Ww) ? 1.f : 0.f;
    float vx1 = (x1 >= 0 && x1 < Ww) ? 1.f : 0.f;
    int y0c = min(max(y0, 0), Hh - 1), y1c = min(max(y1, 0), Hh - 1);
    int x0c = min(max(x0, 0), Ww - 1), x1c = min(max(x1, 0), Ww - 1);
    pa9[kk][sl] = make_int4((y0c * Ww + x0c) * Cc, (y0c * Ww + x1c) * Cc,
                            (y1c * Ww + x0c) * Cc, (y1c * Ww + x1c) * Cc);
    pw9[kk][sl] = make_float4(m * (1.f - wy) * (1.f - wx) * vy0 * vx0,
                              m * (1.f - wy) * wx * vy0 * vx1,
                              m * wy * (1.f - wx) * vy1 * vx0,
                              m * wy * wx * vy1 * vx1);
  }
  __syncthreads();

  f32x16 acc0, acc1;
#pragma unroll
  for (int j = 0; j < 16; ++j) { acc0[j] = 0.f; acc1[j] = 0.f; }

  // weight A-fragment load: wt[((kk*16+cc)*8 + osub)*512 + lane*8]
  auto ldW = [&](int kk, int cc, int which) {
    size_t idx = (size_t)((kk * 16 + cc) * 8 + wv * 2 + which);
    return *(const bf16x8*)(wt + (idx << 9) + (lane << 3));
  };
  // B fragment from LDS: row sB, logical granule 2cc+hi, XOR-swizzled
  auto ldB = [&](int buf, int cc) {
    int g = ((2 * cc + hi) ^ (sB & 7)) << 3;
    return *(const bf16x8*)(&colT[buf][sB * 256 + g]);
  };

  for (int kk = 0; kk < Kk; ++kk) {
    const int buf = kk & 1;
    // ---- fill: 16 burst dwordx4 corner loads, bilinear, swizzled LDS write ----
    {
      int4 a = pa9[kk][fs];
      float4 wq = pw9[kk][fs];
      __bf16* drow = &colT[buf][fs * 256];
#pragma unroll
      for (int it2 = 0; it2 < 4; ++it2) {
        int g = fg + it2 * 8;           // logical granule (8 ch)
        const __bf16* p = itb + g * 8;
        uint4 c00 = *(const uint4*)(p + a.x);
        uint4 c01 = *(const uint4*)(p + a.y);
        uint4 c10 = *(const uint4*)(p + a.z);
        uint4 c11 = *(const uint4*)(p + a.w);
        unsigned u0[4] = {c00.x, c00.y, c00.z, c00.w};
        unsigned u1[4] = {c01.x, c01.y, c01.z, c01.w};
        unsigned u2[4] = {c10.x, c10.y, c10.z, c10.w};
        unsigned u3[4] = {c11.x, c11.y, c11.z, c11.w};
        bf16x8 rv;
#pragma unroll
        for (int w = 0; w < 4; ++w) {
          f32x2 r = up2(u0[w]) * wq.x + up2(u1[w]) * wq.y +
                    up2(u2[w]) * wq.z + up2(u3[w]) * wq.w;
          rv[2 * w] = (__bf16)r.x;
          rv[2 * w + 1] = (__bf16)r.y;
        }
        *(bf16x8*)(drow + ((g ^ (fs & 7)) << 3)) = rv;
      }
    }

    // ---- W preload: ENTIRE tap slice for this wave, issued pre-barrier.
    // The barrier's "memory" clobber pins these before it; latency hides
    // under the other waves' bilinear + barrier skew. 32 x dwordx4 = 128 VGPR.
    bf16x8 Wr0[16], Wr1[16];
#pragma unroll
    for (int cc = 0; cc < 16; ++cc) {
      Wr0[cc] = ldW(kk, cc, 0);
      Wr1[cc] = ldW(kk, cc, 1);
    }
    barrier_lgkm();

    // ---- compute: global-load-free; LDS B prefetch-2 (3-slot rotation) ----
    bf16x8 Bp[3];
    Bp[0] = ldB(buf, 0);
    Bp[1] = ldB(buf, 1);
#pragma unroll
    for (int cc = 0; cc < 16; ++cc) {
      if (cc < 14) Bp[(cc + 2) % 3] = ldB(buf, cc + 2);
      acc0 = __builtin_amdgcn_mfma_f32_32x32x16_bf16(Wr0[cc], Bp[cc % 3], acc0, 0, 0, 0);
      acc1 = __builtin_amdgcn_mfma_f32_32x32x16_bf16(Wr1[cc], Bp[cc % 3], acc1, 0, 0, 0);
    }
  }

  // ---- epilogue: direct store with bias ----
  // D mapping (32x32): col(s)=lane&31, row(o-off)=(r&3)+8*(r>>2)+4*(lane>>5)
  float* ob = out + (size_t)b * Oo * Ss + s0 + sB;
#pragma unroll
  for (int os = 0; os < 2; ++os) {
#pragma unroll
    for (int r = 0; r < 16; ++r) {
      int o = wv * 64 + os * 32 + (r & 3) + 8 * (r >> 2) + 4 * hi;
      float v = (os ? acc1[r] : acc0[r]) + bias[o];
      ob[(size_t)o * Ss] = v;
    }
  }
}

extern "C" void kernel_launch(void* const* d_in, const int* in_sizes, int n_in,
                              void* d_out, int out_size, void* d_ws, size_t ws_size,
                              hipStream_t stream) {
  (void)in_sizes; (void)n_in; (void)out_size; (void)ws_size;
  const float* inp = (const float*)d_in[0];
  const float* offset = (const float*)d_in[1];
  const float* mask = (const float*)d_in[2];
  const float* weight = (const float*)d_in[3];
  const float* bias = (const float*)d_in[4];
  float* out = (float*)d_out;

  __bf16* it = (__bf16*)d_ws;                                      // 9,437,184 B
  __bf16* wt = (__bf16*)((char*)d_ws + (size_t)Bb * Ss * Cc * 2);  // 1,179,648 B

  prep<<<3456, 256, 0, stream>>>(inp, weight, it, wt);
  dcn_main<<<dim3(288, Bb), 256, 0, stream>>>(it, wt, offset, mask, bias, out);
}

// Round 7
// 128.973 us; speedup vs baseline: 1.1194x; 1.0819x over previous
//
#include <hip/hip_runtime.h>
#include <hip/hip_bf16.h>

// DCNv2 forward: B=2, C=256, H=W=96, O=256, K=3x3, stride=1, pad=1, dil=1.
// Pipeline:
//  K1 prep     : (a) input NCHW fp32 -> NHWC bf16,
//                (b) weight -> bf16 32x32-FRAGMENT order wt[kk][cc16][osub][lane][8]
//  K2 dcn_main : per tap: burst-fill 32s x 256ch tap tile into LDS (1 barrier),
//                then 16 chunks of mfma_32x32x16 with register-prefetched weights
//                (R5 schedule, best measured 55.5us) + R12 TAP-PHASE STAGGER.
// R12 theory: convoy-bound. Evidence: elapsed invariant to waves/SIMD (R8 2x ->
//   null) and to bytes (R9 0.67x -> slower), but sensitive to burstiness
//   (R10 32-load burst -> 68us). No average meter pinned (VALU 21%, MFMA 15%,
//   L2 ~18TB/s ~52%). Co-resident blocks run identical schedules in phase ->
//   all waves on a CU flood L2 with fill gathers simultaneously (queueing
//   delay ~ N waves -> TLP null), then idle together. Fix: stagger tap start
//   kk0 = (5bx+3by)%9 so neighbor blocks' fill bursts land under each other's
//   compute phases. Tap sum is commutative (fp32 reorder ~2^-24 vs 2^-7 floor).
// R10/R11 lesson: const __restrict__ lets the compiler REMATERIALIZE "preloaded"
//   W after a fence instead of holding 128 VGPR (VGPR=108, dur 68us). Register-
//   resident cross-phase operands are compiler-hostile; keep lookahead-1.
// R9 lesson: cutting W bytes 2x but losing dbuf/blocks -> 78us. Not BW-avg-bound.
// R8 lesson: occupancy 2x spill-free -> null. R7: tight launch_bounds -> spill.

#define Hh 96
#define Ww 96
#define Cc 256
#define Oo 256
#define Bb 2
#define Kk 9
#define Ss (Hh * Ww)          // 9216
#define CKTOT (Cc * Kk)       // 2304

typedef __bf16 bf16x8 __attribute__((ext_vector_type(8)));
typedef __bf16 bf16x2v __attribute__((ext_vector_type(2)));
typedef float f32x16 __attribute__((ext_vector_type(16)));
typedef float f32x2 __attribute__((ext_vector_type(2)));

__device__ __forceinline__ f32x2 up2(unsigned u) {
  f32x2 r;
  r.x = __uint_as_float(u << 16);
  r.y = __uint_as_float(u & 0xffff0000u);
  return r;
}

// barrier with LDS drain only — prefetched global loads stay in flight.
// simm16 0xC07F = lgkmcnt(0), expcnt(0), vmcnt(63)=no-wait.
__device__ __forceinline__ void barrier_lgkm() {
  asm volatile("" ::: "memory");
  __builtin_amdgcn_s_waitcnt(0xC07F);
  __builtin_amdgcn_s_barrier();
  asm volatile("" ::: "memory");
}

// ---------------- K1: merged prep ----------------
// blocks [0,1152)    : transpose NCHW fp32 -> NHWC bf16
// blocks [1152,3456) : weight repack to 32x32 A-fragment order:
//   wt[kk][cc][osub][lane][j]: o = osub*32 + (lane&31), ch = cc*16 + (lane>>5)*8 + j
__global__ __launch_bounds__(256) void prep(const float* __restrict__ inp,
                                            const float* __restrict__ wsrc,
                                            __bf16* __restrict__ it,
                                            __bf16* __restrict__ wt) {
  __shared__ float tile[64][65];
  const int bx = blockIdx.x;
  const int tid = threadIdx.x;

  if (bx < 1152) {
    const int hw0 = (bx % 144) * 64;
    const int c0 = ((bx / 144) & 3) * 64;
    const int b = bx / 576;
    const int hw_l = tid & 63, cr = tid >> 6;
    const float* src = inp + ((size_t)(b * Cc + c0) * Ss) + hw0;
#pragma unroll
    for (int r = 0; r < 16; ++r) {
      int c_l = r * 4 + cr;
      tile[c_l][hw_l] = src[(size_t)c_l * Ss + hw_l];
    }
    __syncthreads();
    const int cp = (tid & 31) * 2, hr = tid >> 5;
    __bf16* dst = it + ((size_t)(b * Ss + hw0) * Cc) + c0;
#pragma unroll
    for (int r = 0; r < 8; ++r) {
      int hw_s = r * 8 + hr;
      bf16x2v p;
      p.x = (__bf16)tile[cp][hw_s];
      p.y = (__bf16)tile[cp + 1][hw_s];
      *(bf16x2v*)(dst + (size_t)hw_s * Cc + cp) = p;
    }
  } else {
    int i = (bx - 1152) * 256 + tid;  // i < Oo*CKTOT = 589824
    int j = i & 7;
    int l = (i >> 3) & 63;
    int osub = (i >> 9) & 7;
    int cc = (i >> 12) & 15;
    int kk = i >> 16;
    int o = osub * 32 + (l & 31);
    int ch = cc * 16 + ((l >> 5) << 3) + j;
    wt[i] = (__bf16)wsrc[(o * Cc + ch) * Kk + kk];
  }
}

// ---------------- K2: fused sample + GEMM ----------------
// grid (288, 2): x = 32-s tile (XCD-swizzled), y = batch.
// 256 thr = 4 waves; wave wv covers o in [wv*64, wv*64+64); block = 32s x 256 O.
__global__ __launch_bounds__(256, 3) void dcn_main(
    const __bf16* __restrict__ it,     // [B][S][C] bf16
    const __bf16* __restrict__ wt,     // 32x32-fragment-order weights
    const float* __restrict__ offset,  // [B][18][S]
    const float* __restrict__ mask,    // [B][9][S]
    const float* __restrict__ bias,    // [O]
    float* __restrict__ out)           // [B][O][S]
{
  __shared__ __bf16 colT[2][32 * 256];  // dbuf tap tile, XOR-swizzled granules
  __shared__ int4 pa9[9][32];           // per-tap corner offsets (elements)
  __shared__ float4 pw9[9][32];         // per-tap corner weights (mask+valid folded)

  const int tid = threadIdx.x;
  // XCD swizzle: XCD j gets 36 contiguous 32-s tiles (~2.6MB L2 working set).
  const int tile = (blockIdx.x & 7) * 36 + (blockIdx.x >> 3);
  const int s0 = tile * 32;
  const int b = blockIdx.y;
  const int lane = tid & 63;
  const int wv = tid >> 6;            // 4 waves -> 64 O each
  const int sB = lane & 31;           // B-frag / C-frag spatial lane
  const int hi = lane >> 5;
  const int fs = tid >> 3;            // fill: s-row 0..31
  const int fg = tid & 7;             // fill: granule group 0..7

  // R12: tap-phase stagger. Co-resident blocks (consecutive bx, both by) start
  // the commutative tap loop at different kk so their fill bursts interleave
  // with each other's compute phases instead of convoying on the L2 queues.
  const int kk0 = (5 * blockIdx.x + 3 * blockIdx.y) % 9;

  const __bf16* itb = it + (size_t)b * Ss * Cc;

  // ---- bilinear params for all 9 taps up front ----
  for (int idx = tid; idx < 9 * 32; idx += 256) {
    int kk = idx >> 5;
    int sl = idx & 31;
    int s = s0 + sl;
    int ho = s / Ww;
    int wo = s - ho * Ww;
    float dy = offset[((size_t)(b * 18 + 2 * kk)) * Ss + s];
    float dx = offset[((size_t)(b * 18 + 2 * kk + 1)) * Ss + s];
    float m = mask[((size_t)(b * 9 + kk)) * Ss + s];
    float y = (float)(ho - 1 + kk / 3) + dy;
    float x = (float)(wo - 1 + kk % 3) + dx;
    float fy = floorf(y), fx = floorf(x);
    int y0 = (int)fy, x0 = (int)fx;
    float wy = y - fy, wx = x - fx;
    int y1 = y0 + 1, x1 = x0 + 1;
    float vy0 = (y0 >= 0 && y0 < Hh) ? 1.f : 0.f;
    float vy1 = (y1 >= 0 && y1 < Hh) ? 1.f : 0.f;
    float vx0 = (x0 >= 0 && x0 < Ww) ? 1.f : 0.f;
    float vx1 = (x1 >= 0 && x1 < Ww) ? 1.f : 0.f;
    int y0c = min(max(y0, 0), Hh - 1), y1c = min(max(y1, 0), Hh - 1);
    int x0c = min(max(x0, 0), Ww - 1), x1c = min(max(x1, 0), Ww - 1);
    pa9[kk][sl] = make_int4((y0c * Ww + x0c) * Cc, (y0c * Ww + x1c) * Cc,
                            (y1c * Ww + x0c) * Cc, (y1c * Ww + x1c) * Cc);
    pw9[kk][sl] = make_float4(m * (1.f - wy) * (1.f - wx) * vy0 * vx0,
                              m * (1.f - wy) * wx * vy0 * vx1,
                              m * wy * (1.f - wx) * vy1 * vx0,
                              m * wy * wx * vy1 * vx1);
  }
  __syncthreads();

  f32x16 acc0, acc1;
#pragma unroll
  for (int j = 0; j < 16; ++j) { acc0[j] = 0.f; acc1[j] = 0.f; }

  // weight A-fragment load: wt[((kk*16+cc)*8 + osub)*512 + lane*8]
  auto ldW = [&](int kk, int cc, int which) {
    size_t idx = (size_t)((kk * 16 + cc) * 8 + wv * 2 + which);
    return *(const bf16x8*)(wt + (idx << 9) + (lane << 3));
  };
  // B fragment from LDS: row sB, logical granule 2cc+hi, XOR-swizzled
  auto ldB = [&](int buf, int cc) {
    int g = ((2 * cc + hi) ^ (sB & 7)) << 3;
    return *(const bf16x8*)(&colT[buf][sB * 256 + g]);
  };

  for (int t = 0; t < Kk; ++t) {
    int kk = t + kk0;
    if (kk >= Kk) kk -= Kk;           // staggered tap order (sum commutes)
    const int buf = t & 1;
    // ---- fill: 16 burst dwordx4 corner loads, bilinear, swizzled LDS write ----
    {
      int4 a = pa9[kk][fs];
      float4 wq = pw9[kk][fs];
      __bf16* drow = &colT[buf][fs * 256];
#pragma unroll
      for (int it2 = 0; it2 < 4; ++it2) {
        int g = fg + it2 * 8;           // logical granule (8 ch)
        const __bf16* p = itb + g * 8;
        uint4 c00 = *(const uint4*)(p + a.x);
        uint4 c01 = *(const uint4*)(p + a.y);
        uint4 c10 = *(const uint4*)(p + a.z);
        uint4 c11 = *(const uint4*)(p + a.w);
        unsigned u0[4] = {c00.x, c00.y, c00.z, c00.w};
        unsigned u1[4] = {c01.x, c01.y, c01.z, c01.w};
        unsigned u2[4] = {c10.x, c10.y, c10.z, c10.w};
        unsigned u3[4] = {c11.x, c11.y, c11.z, c11.w};
        bf16x8 rv;
#pragma unroll
        for (int w = 0; w < 4; ++w) {
          f32x2 r = up2(u0[w]) * wq.x + up2(u1[w]) * wq.y +
                    up2(u2[w]) * wq.z + up2(u3[w]) * wq.w;
          rv[2 * w] = (__bf16)r.x;
          rv[2 * w + 1] = (__bf16)r.y;
        }
        *(bf16x8*)(drow + ((g ^ (fs & 7)) << 3)) = rv;
      }
    }
    // chunk-0 weights issued pre-barrier; lgkm-only barrier keeps them in flight
    bf16x8 Wacur = ldW(kk, 0, 0);
    bf16x8 Wbcur = ldW(kk, 0, 1);
    barrier_lgkm();

    // ---- compute: 16 chunks, register lookahead, no barriers ----
    bf16x8 Bcur = ldB(buf, 0);
#pragma unroll
    for (int cc = 0; cc < 16; ++cc) {
      bf16x8 Bn, Wan, Wbn;
      if (cc < 15) {
        Bn = ldB(buf, cc + 1);
        Wan = ldW(kk, cc + 1, 0);
        Wbn = ldW(kk, cc + 1, 1);
      }
      acc0 = __builtin_amdgcn_mfma_f32_32x32x16_bf16(Wacur, Bcur, acc0, 0, 0, 0);
      acc1 = __builtin_amdgcn_mfma_f32_32x32x16_bf16(Wbcur, Bcur, acc1, 0, 0, 0);
      if (cc < 15) {
        Bcur = Bn;
        Wacur = Wan;
        Wbcur = Wbn;
      }
    }
  }

  // ---- epilogue: direct store with bias ----
  // D mapping (32x32): col(s)=lane&31, row(o-off)=(r&3)+8*(r>>2)+4*(lane>>5)
  float* ob = out + (size_t)b * Oo * Ss + s0 + sB;
#pragma unroll
  for (int os = 0; os < 2; ++os) {
#pragma unroll
    for (int r = 0; r < 16; ++r) {
      int o = wv * 64 + os * 32 + (r & 3) + 8 * (r >> 2) + 4 * hi;
      float v = (os ? acc1[r] : acc0[r]) + bias[o];
      ob[(size_t)o * Ss] = v;
    }
  }
}

extern "C" void kernel_launch(void* const* d_in, const int* in_sizes, int n_in,
                              void* d_out, int out_size, void* d_ws, size_t ws_size,
                              hipStream_t stream) {
  (void)in_sizes; (void)n_in; (void)out_size; (void)ws_size;
  const float* inp = (const float*)d_in[0];
  const float* offset = (const float*)d_in[1];
  const float* mask = (const float*)d_in[2];
  const float* weight = (const float*)d_in[3];
  const float* bias = (const float*)d_in[4];
  float* out = (float*)d_out;

  __bf16* it = (__bf16*)d_ws;                                      // 9,437,184 B
  __bf16* wt = (__bf16*)((char*)d_ws + (size_t)Bb * Ss * Cc * 2);  // 1,179,648 B

  prep<<<3456, 256, 0, stream>>>(inp, weight, it, wt);
  dcn_main<<<dim3(288, Bb), 256, 0, stream>>>(it, wt, offset, mask, bias, out);
}